// Round 1
// baseline (800.729 us; speedup 1.0000x reference)
//
#include <hip/hip_runtime.h>

// 2-layer GRU (B=1024, T=512, F=128, H=64) + ReLU + FC(64->18), fp32 in/out.
//
// R4: fuse P (gx GEMM) into L0. P's MFMA C-layout output (row=q*4+i, col=gc)
// is exactly the acc-init layout L0 needs per wave wv -> gx never leaves
// registers. Eliminates the 24KiB gxring and half of all b128 LDS traffic
// (48 -> 24 per tick/block), shrinks the barrier cohort 12 -> 8 waves.
//   waves 0-3 (A): h0(t) = GRUcell(x(t)@Wih0.T (in-reg), h0(t-1)); 18 MFMA.
//                  distance-2 HBM prefetch: xf holds x(t) (pre-converted),
//                  xf32 holds x(t+1); loads x(t+2) issued each tick.
//   waves 4-7 (B): h1(t-1) = GRUcell(h0(t-1), h1(t-2)); 12 MFMA.
// 4-deep MFMA chains split into 2+2 with a final f32x4 add (halves dependent
// MFMA latency). One __syncthreads per tick. setprio(1) around MFMA clusters
// (role-split waves share a SIMD -> scheduler has something to arbitrate).
// VGPR ~190 (role A) is fine: 512 thr = 8 waves = 2/SIMD -> 256 VGPR budget.

#define Tn 512
#define Fn 128
#define Hn 64
#define An 18
// padded h row stride (halves): 72 -> 144B rows, start-bank gcd 4 (cheap)
#define HS 72

typedef _Float16 half8 __attribute__((ext_vector_type(8)));
typedef float f32x4 __attribute__((ext_vector_type(4)));

#define MFMA(a, b, c) __builtin_amdgcn_mfma_f32_16x16x32_f16((a), (b), (c), 0, 0, 0)

// Clamp-free: exp2(+-inf) saturates, rcp(inf)->0.
static __device__ __forceinline__ float sigm(float x) {
    return __builtin_amdgcn_rcpf(1.0f + __builtin_amdgcn_exp2f(-1.4426950408889634f * x));
}
static __device__ __forceinline__ float tanh_f(float x) {
    return 2.0f * __builtin_amdgcn_rcpf(1.0f + __builtin_amdgcn_exp2f(-2.8853900817779268f * x)) - 1.0f;
}

__global__ __launch_bounds__(512) void gru_fused(
    const float* __restrict__ state,
    const float* __restrict__ Wih0, const float* __restrict__ Whh0,
    const float* __restrict__ bih0, const float* __restrict__ bhh0,
    const float* __restrict__ Wih1, const float* __restrict__ Whh1,
    const float* __restrict__ bih1, const float* __restrict__ bhh1,
    const float* __restrict__ fcw, const float* __restrict__ fcb,
    float* __restrict__ out)
{
    const int tid  = threadIdx.x;
    const int wv8  = tid >> 6;
    const int lane = tid & 63, c = lane & 15, q = lane >> 4;
    const int wv   = wv8 & 3;
    const int r0   = blockIdx.x * 16;
    const int gc   = wv * 16 + c;
    const int roleB = (wv8 >= 4);

    __shared__ __align__(16) _Float16 h0buf[2][16 * HS];        // 4.5 KiB
    __shared__ __align__(16) _Float16 h1buf[2][16 * HS];        // 4.5 KiB
    __shared__ float fbuf[16 * 64];                             // 4 KiB

    for (int i = tid; i < 2 * 16 * HS; i += 512) {
        (&h0buf[0][0])[i] = (_Float16)0.0f;
        (&h1buf[0][0])[i] = (_Float16)0.0f;
    }

    // Weight fragments (B-operand layout: lane(c,q) holds W[n=g][k=ks*32+q*8+j]):
    //  A: W[gsel*4+ks]   = Wih0 (k=128, 4 ksteps)
    //     W[12+gsel*2+ks]= Whh0 (k=64, 2 ksteps)
    //  B: W[gsel*2+ks]   = Wih1 ; W[6+gsel*2+ks] = Whh1
    half8 W[18];
    f32x4 bias0, bias1, bias2, bias3;
    f32x4 xf32[8];
    half8 xf[4];
    f32x4 hreg = {0.f, 0.f, 0.f, 0.f};
    const float* srow = state + (size_t)(r0 + c) * (Tn * Fn);

    if (!roleB) {
#pragma unroll
        for (int gsel = 0; gsel < 3; ++gsel) {
            const int g = gsel * 64 + gc;
#pragma unroll
            for (int ks = 0; ks < 4; ++ks) {
                const float* p = Wih0 + g * Fn + ks * 32 + q * 8;
#pragma unroll
                for (int j = 0; j < 8; ++j) W[gsel * 4 + ks][j] = (_Float16)p[j];
            }
#pragma unroll
            for (int ks = 0; ks < 2; ++ks) {
                const float* p = Whh0 + g * Hn + ks * 32 + q * 8;
#pragma unroll
                for (int j = 0; j < 8; ++j) W[12 + gsel * 2 + ks][j] = (_Float16)p[j];
            }
        }
        {
            const float b0 = bih0[gc] + bhh0[gc];
            const float b1 = bih0[64 + gc] + bhh0[64 + gc];
            const float b2 = bih0[128 + gc];
            const float b3 = bhh0[128 + gc];
            bias0 = (f32x4){b0, b0, b0, b0};
            bias1 = (f32x4){b1, b1, b1, b1};
            bias2 = (f32x4){b2, b2, b2, b2};
            bias3 = (f32x4){b3, b3, b3, b3};
        }
        // prologue: x(0) -> xf (converted); x(1) -> xf32
#pragma unroll
        for (int ks = 0; ks < 4; ++ks) {
            xf32[2 * ks]     = *(const f32x4*)(srow + ks * 32 + q * 8);
            xf32[2 * ks + 1] = *(const f32x4*)(srow + ks * 32 + q * 8 + 4);
        }
#pragma unroll
        for (int ks = 0; ks < 4; ++ks)
#pragma unroll
            for (int i = 0; i < 4; ++i) {
                xf[ks][i]     = (_Float16)xf32[2 * ks][i];
                xf[ks][4 + i] = (_Float16)xf32[2 * ks + 1][i];
            }
#pragma unroll
        for (int ks = 0; ks < 4; ++ks) {
            xf32[2 * ks]     = *(const f32x4*)(srow + Fn + ks * 32 + q * 8);
            xf32[2 * ks + 1] = *(const f32x4*)(srow + Fn + ks * 32 + q * 8 + 4);
        }
    } else {
#pragma unroll
        for (int gsel = 0; gsel < 3; ++gsel) {
            const int g = gsel * 64 + gc;
#pragma unroll
            for (int ks = 0; ks < 2; ++ks) {
                const float* pa = Wih1 + g * Hn + ks * 32 + q * 8;
                const float* pb = Whh1 + g * Hn + ks * 32 + q * 8;
#pragma unroll
                for (int j = 0; j < 8; ++j) {
                    W[gsel * 2 + ks][j]     = (_Float16)pa[j];
                    W[6 + gsel * 2 + ks][j] = (_Float16)pb[j];
                }
            }
        }
        const float br_ = bih1[gc] + bhh1[gc];
        const float bz_ = bih1[64 + gc] + bhh1[64 + gc];
        const float bxn = bih1[128 + gc];
        const float bhn = bhh1[128 + gc];
        bias0 = (f32x4){br_, br_, br_, br_};
        bias1 = (f32x4){bz_, bz_, bz_, bz_};
        bias2 = (f32x4){bxn, bxn, bxn, bxn};
        bias3 = (f32x4){bhn, bhn, bhn, bhn};
    }

    const int ardr = c * HS + q * 8;        // A-frag read base (+32 for kstep 1)
    const int wrow = (q * 4) * HS + gc;     // C-layout write base (+i*HS)
    const f32x4 z4 = {0.f, 0.f, 0.f, 0.f};

    // Tick t: A makes h0(t) (t<Tn); B makes h1(t-1) (t>=1)
    for (int t = 0; t <= Tn; ++t) {
        __syncthreads();
        const int pr = (t & 1) ^ 1, pw = t & 1;
        if (!roleB) {
            if (t < Tn) {
                const half8 hf0 = *(const half8*)&h0buf[pr][ardr];
                const half8 hf1 = *(const half8*)&h0buf[pr][ardr + 32];
                __builtin_amdgcn_s_setprio(1);
                // gx chains (pure register, issue immediately at tick start)
                f32x4 ar = MFMA(xf[0], W[0], bias0);  ar = MFMA(xf[1], W[1], ar);
                f32x4 az = MFMA(xf[0], W[4], bias1);  az = MFMA(xf[1], W[5], az);
                f32x4 an = MFMA(xf[0], W[8], bias2);  an = MFMA(xf[1], W[9], an);
                f32x4 br = MFMA(xf[2], W[2], z4);     br = MFMA(xf[3], W[3], br);
                f32x4 bz = MFMA(xf[2], W[6], z4);     bz = MFMA(xf[3], W[7], bz);
                f32x4 bn = MFMA(xf[2], W[10], z4);    bn = MFMA(xf[3], W[11], bn);
                // hh chains (wait on LDS h0(t-1), overlapped with gx issue)
                br = MFMA(hf0, W[12], br);  br = MFMA(hf1, W[13], br);
                bz = MFMA(hf0, W[14], bz);  bz = MFMA(hf1, W[15], bz);
                f32x4 hn = MFMA(hf0, W[16], bias3);  hn = MFMA(hf1, W[17], hn);
                __builtin_amdgcn_s_setprio(0);
                // next-x convert + distance-2 prefetch (independent of MFMAs)
                if (t < Tn - 1) {
#pragma unroll
                    for (int ks = 0; ks < 4; ++ks)
#pragma unroll
                        for (int i = 0; i < 4; ++i) {
                            xf[ks][i]     = (_Float16)xf32[2 * ks][i];
                            xf[ks][4 + i] = (_Float16)xf32[2 * ks + 1][i];
                        }
                    const int tnx = (t + 2 < Tn) ? (t + 2) : (Tn - 1);
#pragma unroll
                    for (int ks = 0; ks < 4; ++ks) {
                        xf32[2 * ks]     = *(const f32x4*)(srow + (size_t)tnx * Fn + ks * 32 + q * 8);
                        xf32[2 * ks + 1] = *(const f32x4*)(srow + (size_t)tnx * Fn + ks * 32 + q * 8 + 4);
                    }
                }
                const f32x4 accr  = ar + br;
                const f32x4 accz  = az + bz;
                const f32x4 accxn = an + bn;
#pragma unroll
                for (int i = 0; i < 4; ++i) {
                    const float rg = sigm(accr[i]);
                    const float zg = sigm(accz[i]);
                    const float ng = tanh_f(accxn[i] + rg * hn[i]);
                    hreg[i] = ng + zg * (hreg[i] - ng);
                }
#pragma unroll
                for (int i = 0; i < 4; ++i) h0buf[pw][wrow + i * HS] = (_Float16)hreg[i];
            }
        } else {
            if (t >= 1) {
                const half8 xf0 = *(const half8*)&h0buf[pr][ardr];
                const half8 xf1 = *(const half8*)&h0buf[pr][ardr + 32];
                const half8 hf0 = *(const half8*)&h1buf[pw][ardr];
                const half8 hf1 = *(const half8*)&h1buf[pw][ardr + 32];
                __builtin_amdgcn_s_setprio(1);
                f32x4 xr = MFMA(xf0, W[0], bias0);  xr = MFMA(xf1, W[1], xr);
                f32x4 xz = MFMA(xf0, W[2], bias1);  xz = MFMA(xf1, W[3], xz);
                f32x4 xn = MFMA(xf0, W[4], bias2);  xn = MFMA(xf1, W[5], xn);
                f32x4 hr = MFMA(hf0, W[6], z4);     hr = MFMA(hf1, W[7], hr);
                f32x4 hz = MFMA(hf0, W[8], z4);     hz = MFMA(hf1, W[9], hz);
                f32x4 hn = MFMA(hf0, W[10], bias3); hn = MFMA(hf1, W[11], hn);
                __builtin_amdgcn_s_setprio(0);
                const f32x4 accr = xr + hr;
                const f32x4 accz = xz + hz;
#pragma unroll
                for (int i = 0; i < 4; ++i) {
                    const float rg = sigm(accr[i]);
                    const float zg = sigm(accz[i]);
                    const float ng = tanh_f(xn[i] + rg * hn[i]);
                    hreg[i] = ng + zg * (hreg[i] - ng);
                }
#pragma unroll
                for (int i = 0; i < 4; ++i) h1buf[pr][wrow + i * HS] = (_Float16)hreg[i];
            }
        }
    }

    // epilogue: relu(h1_final) @ fc3_w.T + fc3_b   (role B holds h1(Tn-1))
    if (roleB) {
#pragma unroll
        for (int i = 0; i < 4; ++i) fbuf[(q * 4 + i) * 64 + gc] = fmaxf(hreg[i], 0.0f);
    }
    __syncthreads();
    for (int idx = tid; idx < 16 * An; idx += 512) {
        const int row = idx / An, a = idx - row * An;
        float acc = fcb[a];
#pragma unroll 16
        for (int k = 0; k < Hn; ++k) acc += fbuf[row * 64 + k] * fcw[a * Hn + k];
        out[(size_t)(r0 + row) * An + a] = acc;
    }
}

extern "C" void kernel_launch(void* const* d_in, const int* in_sizes, int n_in,
                              void* d_out, int out_size, void* d_ws, size_t ws_size,
                              hipStream_t stream) {
    const float* state = (const float*)d_in[0];
    const float* Wih0  = (const float*)d_in[1];
    const float* Whh0  = (const float*)d_in[2];
    const float* bih0  = (const float*)d_in[3];
    const float* bhh0  = (const float*)d_in[4];
    const float* Wih1  = (const float*)d_in[5];
    const float* Whh1  = (const float*)d_in[6];
    const float* bih1  = (const float*)d_in[7];
    const float* bhh1  = (const float*)d_in[8];
    const float* fcw   = (const float*)d_in[9];
    const float* fcb   = (const float*)d_in[10];
    float* out = (float*)d_out;

    gru_fused<<<64, 512, 0, stream>>>(state, Wih0, Whh0, bih0, bhh0,
                                      Wih1, Whh1, bih1, bhh1, fcw, fcb, out);
}